// Round 8
// baseline (346.532 us; speedup 1.0000x reference)
//
#include <hip/hip_runtime.h>

typedef __bf16 bf16x8 __attribute__((ext_vector_type(8)));
typedef __bf16 bf16x4 __attribute__((ext_vector_type(4)));
typedef float  f32x4  __attribute__((ext_vector_type(4)));

// ws layout (bf16 elements), all in MFMA b-fragment order [kstep][ntile][lane][8]
// W2/WQ/WH2 are pre-scaled by the upstream LN gain (LN folding).
#define OFF_W1  0        // 20 ksteps * 16 nt * 512  = 163840   (s_w1 640x256)
#define OFF_W2  163840   //  8 * 16 * 512            =  65536   (g_s1*s_w2 256x256)
#define OFF_WQ  229376   //  8 *  8 * 512            =  32768   (g_s2*(qd|qe) 256x128)
#define OFF_WH1 262144   //  1 *  8 * 512            =   4096   (h_w1 10->32 zero-pad x128)
#define OFF_WH2 266240   //  4 *  8 * 512            =  16384   (g_h1*h_w2 128x128)
#define WS_ELEMS 282624
// fp32 fold constants appended after the bf16 region (offsets in floats):
#define CE_CH2 0
#define CE_EH2 128
#define CE_C2  256
#define CE_E2  512
#define CE_CQ  768
#define CE_EQ  896

__global__ __launch_bounds__(256) void prep_kernel(
    const float* __restrict__ s_w1, const float* __restrict__ s_w2,
    const float* __restrict__ qd_w, const float* __restrict__ qe_w,
    const float* __restrict__ h_w1, const float* __restrict__ h_w2,
    const float* __restrict__ h_g1, const float* __restrict__ s_g1,
    const float* __restrict__ s_g2,
    __bf16* __restrict__ wsb)
{
  int idx = blockIdx.x * 256 + threadIdx.x;
  if (idx >= WS_ELEMS) return;
  float val = 0.f;
  if (idx < OFF_W2) {                       // W1: K=640, N=256
    int t = idx;
    int j = t & 7, l = (t >> 3) & 63, rest = t >> 9;
    int nt = rest & 15, ks = rest >> 4;
    int k = ks * 32 + (l >> 4) * 8 + j, n = nt * 16 + (l & 15);
    val = s_w1[k * 256 + n];
  } else if (idx < OFF_WQ) {                // W2: K=256, N=256, scaled by g_s1[k]
    int t = idx - OFF_W2;
    int j = t & 7, l = (t >> 3) & 63, rest = t >> 9;
    int nt = rest & 15, ks = rest >> 4;
    int k = ks * 32 + (l >> 4) * 8 + j, n = nt * 16 + (l & 15);
    val = s_w2[k * 256 + n] * s_g1[k];
  } else if (idx < OFF_WH1) {               // Wq: K=256, N=128, n = 2a+sel, scaled by g_s2[k]
    int t = idx - OFF_WQ;
    int j = t & 7, l = (t >> 3) & 63, rest = t >> 9;
    int nt = rest & 7, ks = rest >> 3;
    int k = ks * 32 + (l >> 4) * 8 + j, n = nt * 16 + (l & 15);
    int a = n >> 1;
    val = ((n & 1) ? qe_w[k * 64 + a] : qd_w[k * 64 + a]) * s_g2[k];
  } else if (idx < OFF_WH2) {               // Wh1: K=10 padded to 32, N=128
    int t = idx - OFF_WH1;
    int j = t & 7, l = (t >> 3) & 63, rest = t >> 9;
    int nt = rest & 7;
    int k = (l >> 4) * 8 + j, n = nt * 16 + (l & 15);
    val = (k < 10) ? h_w1[k * 128 + n] : 0.f;
  } else {                                  // Wh2: K=128, N=128, scaled by g_h1[k]
    int t = idx - OFF_WH2;
    int j = t & 7, l = (t >> 3) & 63, rest = t >> 9;
    int nt = rest & 7, ks = rest >> 3;
    int k = ks * 32 + (l >> 4) * 8 + j, n = nt * 16 + (l & 15);
    val = h_w2[k * 128 + n] * h_g1[k];
  }
  wsb[idx] = (__bf16)val;
}

// fold constants: c_n = sum_k g_k W_kn ; e_n = sum_k bb_k W_kn + b_n
__global__ __launch_bounds__(256) void prep_ce(
    const float* __restrict__ h_w2, const float* __restrict__ h_g1,
    const float* __restrict__ h_bb1, const float* __restrict__ h_b2,
    const float* __restrict__ s_w2, const float* __restrict__ s_g1,
    const float* __restrict__ s_bb1, const float* __restrict__ s_b2,
    const float* __restrict__ qd_w, const float* __restrict__ qe_w,
    const float* __restrict__ s_g2, const float* __restrict__ s_bb2,
    const float* __restrict__ qd_b, const float* __restrict__ qe_b,
    float* __restrict__ ce)
{
  int t = blockIdx.x * 256 + threadIdx.x;
  if (t < 128) {                       // c_h2
    float s = 0.f;
    for (int k = 0; k < 128; ++k) s += h_g1[k] * h_w2[k * 128 + t];
    ce[CE_CH2 + t] = s;
  } else if (t < 256) {                // e_h2
    int n = t - 128;
    float s = h_b2[n];
    for (int k = 0; k < 128; ++k) s += h_bb1[k] * h_w2[k * 128 + n];
    ce[t] = s;
  } else if (t < 512) {                // c_2
    int n = t - 256;
    float s = 0.f;
    for (int k = 0; k < 256; ++k) s += s_g1[k] * s_w2[k * 256 + n];
    ce[t] = s;
  } else if (t < 768) {                // e_2
    int n = t - 512;
    float s = s_b2[n];
    for (int k = 0; k < 256; ++k) s += s_bb1[k] * s_w2[k * 256 + n];
    ce[t] = s;
  } else if (t < 896) {                // c_q
    int n = t - 768, a = n >> 1;
    const float* W = (n & 1) ? qe_w : qd_w;
    float s = 0.f;
    for (int k = 0; k < 256; ++k) s += s_g2[k] * W[k * 64 + a];
    ce[t] = s;
  } else if (t < 1024) {               // e_q
    int n = t - 896, a = n >> 1;
    const float* W = (n & 1) ? qe_w : qd_w;
    float s = (n & 1) ? qe_b[a] : qd_b[a];
    for (int k = 0; k < 256; ++k) s += s_bb2[k] * W[k * 64 + a];
    ce[t] = s;
  }
}

// DPP rotate-add: VALU-pipe lane exchange replacing ds_bpermute-based shuffles.
template<int CTRL>
__device__ __forceinline__ float dppadd(float x) {
  int p = __builtin_amdgcn_mov_dpp(__float_as_int(x), CTRL, 0xF, 0xF, true);
  return x + __int_as_float(p);
}
__device__ __forceinline__ float row16_reduce(float x) {
  x = dppadd<0x121>(x);
  x = dppadd<0x122>(x);
  x = dppadd<0x124>(x);
  x = dppadd<0x128>(x);
  return x;
}

// per-row (m = quad*4+r) LN stats from a completed slot: 2 broadcast ds_read_b128
__device__ __forceinline__ void slot_stats(const float* slot, float invW, int quad,
                                           float mu[4], float rs[4]) {
  f32x4 v0 = *(const f32x4*)(slot + quad * 8);
  f32x4 v1 = *(const f32x4*)(slot + quad * 8 + 4);
  float ts[4] = {v0[0], v0[2], v1[0], v1[2]};
  float tq[4] = {v0[1], v0[3], v1[1], v1[3]};
#pragma unroll
  for (int r = 0; r < 4; ++r) {
    mu[r] = ts[r] * invW;
    float var = tq[r] * invW - mu[r] * mu[r];
    rs[r] = rsqrtf(var + 1e-5f);
  }
}

// DPP reduce of x[][] rows + atomic accumulate into slot, then ONE barrier.
template<int NTW>
__device__ __forceinline__ void reduce_slot(float x[NTW][4], float* slot, int lane) {
  const int quad = lane >> 4, ln = lane & 15;
  float s[4] = {0, 0, 0, 0}, q[4] = {0, 0, 0, 0};
#pragma unroll
  for (int i = 0; i < NTW; ++i)
#pragma unroll
    for (int r = 0; r < 4; ++r) { s[r] += x[i][r]; q[r] += x[i][r] * x[i][r]; }
#pragma unroll
  for (int r = 0; r < 4; ++r) { s[r] = row16_reduce(s[r]); q[r] = row16_reduce(q[r]); }
  if (ln == 0) {
#pragma unroll
    for (int r = 0; r < 4; ++r) {
      int m = quad * 4 + r;
      atomicAdd(&slot[2 * m], s[r]);
      atomicAdd(&slot[2 * m + 1], q[r]);
    }
  }
  __syncthreads();
}

// 16 rows (1 mtile), 8 waves split N. A in LDS bf16, B pre-swizzled in global.
template<int KSTEPS, int NT_TOT, int NTW>
__device__ __forceinline__ void run_gemm(const __bf16* A, int astride,
    const bf16x8* __restrict__ Bsw, int wave, int lane, f32x4 acc[NTW])
{
  const int quad = lane >> 4, ln = lane & 15;
  const int ntb = wave * NTW;
  bf16x8 bcur[NTW];
#pragma unroll
  for (int i = 0; i < NTW; ++i) bcur[i] = Bsw[(ntb + i) * 64 + lane];
#pragma unroll
  for (int ks = 0; ks < KSTEPS; ++ks) {
    bf16x8 bnxt[NTW];
    if (ks + 1 < KSTEPS) {
#pragma unroll
      for (int i = 0; i < NTW; ++i)
        bnxt[i] = Bsw[((ks + 1) * NT_TOT + ntb + i) * 64 + lane];
    }
    bf16x8 a = *(const bf16x8*)(A + ln * astride + ks * 32 + quad * 8);
#pragma unroll
    for (int i = 0; i < NTW; ++i)
      acc[i] = __builtin_amdgcn_mfma_f32_16x16x32_bf16(a, bcur[i], acc[i], 0, 0, 0);
    if (ks + 1 < KSTEPS) {
#pragma unroll
      for (int i = 0; i < NTW; ++i) bcur[i] = bnxt[i];
    }
  }
}

// raw epilogue (LN deferred via folding): x = relu(acc+bias); write raw x
// IMMEDIATELY (no dependence on the reduce); reduce -> slot; ONE barrier.
template<int NTW>
__device__ __forceinline__ void epilogue_raw(f32x4 acc[NTW],
    const float* __restrict__ bias,
    __bf16* Adst, int dstride, int dstcol0,
    float* slot, int wave, int lane)
{
  const int quad = lane >> 4, ln = lane & 15;
  float x[NTW][4];
#pragma unroll
  for (int i = 0; i < NTW; ++i) {
    int n = (wave * NTW + i) * 16 + ln;
    float b = bias[n];
#pragma unroll
    for (int r = 0; r < 4; ++r) {
      x[i][r] = fmaxf(acc[i][r] + b, 0.f);
      Adst[(quad * 4 + r) * dstride + dstcol0 + n] = (__bf16)x[i][r];
    }
  }
  reduce_slot<NTW>(x, slot, lane);
}

// fold-consumer raw epilogue: z = rs_prev*(acc - mu_prev*c[n]) + e[n];
// x = relu(z); write raw; reduce -> slot; ONE barrier.
template<int NTW>
__device__ __forceinline__ void epilogue_fold_raw(f32x4 acc[NTW],
    const float* __restrict__ cvec, const float* __restrict__ evec,
    const float* __restrict__ slot_prev, float invWprev,
    __bf16* Adst, int dstride, int dstcol0,
    float* slot, int wave, int lane)
{
  const int quad = lane >> 4, ln = lane & 15;
  float mu[4], rs[4];
  slot_stats(slot_prev, invWprev, quad, mu, rs);
  float x[NTW][4];
#pragma unroll
  for (int i = 0; i < NTW; ++i) {
    int n = (wave * NTW + i) * 16 + ln;
    float c = cvec[n], e = evec[n];
#pragma unroll
    for (int r = 0; r < 4; ++r) {
      float z = fmaf(rs[r], fmaf(-mu[r], c, acc[i][r]), e);
      x[i][r] = fmaxf(z, 0.f);
      Adst[(quad * 4 + r) * dstride + dstcol0 + n] = (__bf16)x[i][r];
    }
  }
  reduce_slot<NTW>(x, slot, lane);
}

__global__ __launch_bounds__(512, 8) void critic_kernel(
    const float* __restrict__ obs, const float* __restrict__ pref,
    const float* __restrict__ h_b1,
    const float* __restrict__ h_g2, const float* __restrict__ h_bb2,
    const float* __restrict__ p_w, const float* __restrict__ p_b,
    const float* __restrict__ p_g, const float* __restrict__ p_bb,
    const float* __restrict__ s_b1,
    const __bf16* __restrict__ wsb, const float* __restrict__ ce,
    float* __restrict__ out)
{
  // 16 rows/block, 8 waves, LDS ~31 KB -> 4 blocks/CU (r1 skeleton).
  // LN folded into next-layer weights: h1/s1/s2 epilogues are single-barrier.
  __shared__ __align__(16) __bf16 A_comb[16 * 648];  // 20736 B (tail reused for x_s2)
  __shared__ __align__(16) __bf16 A_s[16 * 264];     //  8448 B
  __shared__ __align__(16) __bf16 A_h[16 * 40];      //  1280 B
  __shared__ __align__(16) float red4[4][32];        //   512 B (h1,h2,s1,s2 LN slots)

  const int tid = threadIdx.x;
  const int wave = tid >> 6, lane = tid & 63;
  const int rowbase = blockIdx.x * 16;
  __bf16* X2 = A_comb;                               // x_s2 staged as [16][264]

  if (tid < 128) ((float*)red4)[tid] = 0.f;

  // ---------- front-end: each of 8 waves owns 2 rows ----------
  float pw0 = p_w[lane], pw1 = p_w[64 + lane], pb = p_b[lane];
  float pg = p_g[lane], pbb = p_bb[lane];
#pragma unroll
  for (int r = 0; r < 2; ++r) {
    int row = wave * 2 + r;
    int grow = rowbase + row;
    const float* orow = obs + (size_t)grow * 512;
    // obs_wo -> combined cols [0,448): excision at col 68 is float4-aligned.
#pragma unroll
    for (int j = 0; j < 2; ++j) {
      int l = lane + 64 * j;
      if (l < 112) {
        int src4 = (l < 17) ? l : l + 16;   // skip obs cols [68,132)
        float4 v = *(const float4*)(orow + 4 * src4);
        bf16x4 o;
        o[0] = (__bf16)v.x; o[1] = (__bf16)v.y; o[2] = (__bf16)v.z; o[3] = (__bf16)v.w;
        *(bf16x4*)(&A_comb[row * 648 + 4 * l]) = o;
      }
    }
    // histogram of cols [68,132) via ballot
    float w = orow[68 + lane];
    int bi = (int)floorf(w);
    bi = bi < 0 ? 0 : (bi > 9 ? 9 : bi);
    bool valid = (w >= 0.f) && (w <= 10.f);
    float tot = 0.f, mine = 0.f;
#pragma unroll
    for (int b = 0; b < 10; ++b) {
      unsigned long long mk = __ballot(valid && (bi == b));
      float c = (float)__popcll(mk);
      tot += c;
      if (lane == b) mine = c;
    }
    float inv = 1.f / (tot + 1e-8f);
    if (lane < 32) A_h[row * 40 + lane] = (__bf16)((lane < 10) ? mine * inv : 0.f);
    // p layer: 2 -> 64, relu, LN over 64 lanes -> combined cols [576,640)
    float a0 = pref[grow * 2], a1 = pref[grow * 2 + 1];
    float v = fmaxf(fmaf(a0, pw0, fmaf(a1, pw1, pb)), 0.f);
    float s1 = v, s2 = v * v;
    s1 = row16_reduce(s1); s2 = row16_reduce(s2);
    s1 += __shfl_xor(s1, 16, 64); s2 += __shfl_xor(s2, 16, 64);
    s1 += __shfl_xor(s1, 32, 64); s2 += __shfl_xor(s2, 32, 64);
    float mu = s1 * (1.f / 64.f);
    float var = s2 * (1.f / 64.f) - mu * mu;
    float o = (v - mu) * rsqrtf(var + 1e-5f) * pg + pbb;
    A_comb[row * 648 + 576 + lane] = (__bf16)o;
  }
  __syncthreads();

  // ---------- h1: (16x32)@(32x128); raw x_h1 -> A_s; 1 barrier ----------
  {
    f32x4 acc[1] = {};
    run_gemm<1, 8, 1>(A_h, 40, (const bf16x8*)(wsb + OFF_WH1), wave, lane, acc);
    epilogue_raw<1>(acc, h_b1, A_s, 264, 0, red4[0], wave, lane);
  }
  // ---------- h2: (16x128)@(128x128) on raw x_h1 (folded W'); own LN applied
  //             at write (feeds s1's mixed concat) -> A_comb[448,576); 2 barriers ----
  {
    f32x4 acc[1] = {};
    run_gemm<4, 8, 1>(A_s, 264, (const bf16x8*)(wsb + OFF_WH2), wave, lane, acc);
    const int quad = lane >> 4, ln = lane & 15;
    float mu0[4], rs0[4];
    slot_stats(red4[0], 1.f / 128.f, quad, mu0, rs0);
    int n = wave * 16 + ln;
    float c = ce[CE_CH2 + n], e = ce[CE_EH2 + n];
    float x[1][4];
#pragma unroll
    for (int r = 0; r < 4; ++r) {
      float z = fmaf(rs0[r], fmaf(-mu0[r], c, acc[0][r]), e);
      x[0][r] = fmaxf(z, 0.f);
    }
    reduce_slot<1>(x, red4[1], lane);         // barrier 1
    float mu[4], rs[4];
    slot_stats(red4[1], 1.f / 128.f, quad, mu, rs);
    float gg = h_g2[n], bv = h_bb2[n];
#pragma unroll
    for (int r = 0; r < 4; ++r) {
      float o = (x[0][r] - mu[r]) * rs[r] * gg + bv;
      A_comb[(quad * 4 + r) * 648 + 448 + n] = (__bf16)o;
    }
    __syncthreads();                          // barrier 2
  }
  // ---------- s1: (16x640)@(640x256); raw x_s1 -> A_s; 1 barrier ----------
  {
    f32x4 acc[2] = {};
    run_gemm<20, 16, 2>(A_comb, 648, (const bf16x8*)(wsb + OFF_W1), wave, lane, acc);
    epilogue_raw<2>(acc, s_b1, A_s, 264, 0, red4[2], wave, lane);
  }
  // ---------- s2: (16x256)@(256x256) on raw x_s1 (folded); raw x_s2 -> X2; 1 barrier ----
  {
    f32x4 acc[2] = {};
    run_gemm<8, 16, 2>(A_s, 264, (const bf16x8*)(wsb + OFF_W2), wave, lane, acc);
    epilogue_fold_raw<2>(acc, ce + CE_C2, ce + CE_E2, red4[2], 1.f / 256.f,
                         X2, 264, 0, red4[3], wave, lane);
  }
  // ---------- q: (16x256)@(256x128) on raw x_s2 (folded); direct fp32 store ----------
  {
    f32x4 acc[1] = {};
    run_gemm<8, 8, 1>(X2, 264, (const bf16x8*)(wsb + OFF_WQ), wave, lane, acc);
    const int quad = lane >> 4, ln = lane & 15;
    float mu[4], rs[4];
    slot_stats(red4[3], 1.f / 256.f, quad, mu, rs);
    int n = wave * 16 + ln;
    float c = ce[CE_CQ + n], e = ce[CE_EQ + n];
#pragma unroll
    for (int r = 0; r < 4; ++r) {
      int m = quad * 4 + r;
      out[(size_t)(rowbase + m) * 128 + n] = fmaf(rs[r], fmaf(-mu[r], c, acc[0][r]), e);
    }
  }
}

extern "C" void kernel_launch(void* const* d_in, const int* in_sizes, int n_in,
                              void* d_out, int out_size, void* d_ws, size_t ws_size,
                              hipStream_t stream) {
  const float* obs    = (const float*)d_in[0];
  const float* pref   = (const float*)d_in[1];
  const float* h_w1   = (const float*)d_in[2];
  const float* h_b1   = (const float*)d_in[3];
  const float* h_g1   = (const float*)d_in[4];
  const float* h_bb1  = (const float*)d_in[5];
  const float* h_w2   = (const float*)d_in[6];
  const float* h_b2   = (const float*)d_in[7];
  const float* h_g2   = (const float*)d_in[8];
  const float* h_bb2  = (const float*)d_in[9];
  const float* p_w    = (const float*)d_in[10];
  const float* p_b    = (const float*)d_in[11];
  const float* p_g    = (const float*)d_in[12];
  const float* p_bb   = (const float*)d_in[13];
  const float* s_w1   = (const float*)d_in[14];
  const float* s_b1   = (const float*)d_in[15];
  const float* s_g1   = (const float*)d_in[16];
  const float* s_bb1  = (const float*)d_in[17];
  const float* s_w2   = (const float*)d_in[18];
  const float* s_b2   = (const float*)d_in[19];
  const float* s_g2   = (const float*)d_in[20];
  const float* s_bb2  = (const float*)d_in[21];
  const float* qd_w   = (const float*)d_in[22];
  const float* qd_b   = (const float*)d_in[23];
  const float* qe_w   = (const float*)d_in[24];
  const float* qe_b   = (const float*)d_in[25];

  __bf16* wsb = (__bf16*)d_ws;
  float* ce = (float*)(wsb + WS_ELEMS);   // 4 KB of fp32 fold constants
  int B = in_sizes[0] / 512;
  int nblocks = B / 16;

  prep_kernel<<<(WS_ELEMS + 255) / 256, 256, 0, stream>>>(
      s_w1, s_w2, qd_w, qe_w, h_w1, h_w2, h_g1, s_g1, s_g2, wsb);
  prep_ce<<<4, 256, 0, stream>>>(
      h_w2, h_g1, h_bb1, h_b2, s_w2, s_g1, s_bb1, s_b2,
      qd_w, qe_w, s_g2, s_bb2, qd_b, qe_b, ce);
  critic_kernel<<<nblocks, 512, 0, stream>>>(
      obs, pref, h_b1, h_g2, h_bb2, p_w, p_b, p_g, p_bb, s_b1,
      (const __bf16*)wsb, (const float*)ce, (float*)d_out);
}